// Round 1
// baseline (458.210 us; speedup 1.0000x reference)
//
#include <hip/hip_runtime.h>

#define NDIM 128
#define CAP  128   // nodes staged per LDS tile (64 KB)
#define BLK  256

// Build segment offsets ptr[g] = first i with graph_idx[i] >= g, ptr[NG] = N.
// Dtype-robust: probes an odd int32 index near the middle; if the input is
// int64, that slot is a high word == 0; if int32, it's a graph id ~NG/2 != 0.
__global__ void offsets_kernel(const int* __restrict__ g32, int N, int NG,
                               int* __restrict__ ptr) {
    const size_t jprobe = ((size_t)N / 2) | 1;
    const bool is64 = (g32[jprobe] == 0);
    int i = blockIdx.x * blockDim.x + threadIdx.x;
    const int stride = gridDim.x * blockDim.x;
    for (; i < N; i += stride) {
        const int c = is64 ? g32[2 * (size_t)i] : g32[i];
        const int p = (i == 0) ? -1 : (is64 ? g32[2 * (size_t)(i - 1)] : g32[i - 1]);
        for (int g = p + 1; g <= c; ++g) ptr[g] = i;
        if (i == N - 1) {
            for (int g = c + 1; g <= NG; ++g) ptr[g] = N;
        }
    }
}

// One block per graph. 8 groups x 32 lanes; group handles node j (j % 8 == grp),
// lane gl covers dims [4*gl, 4*gl+4). Phase A: stage tile to LDS + logits.
// Phase B: softmax weights from LDS, accumulate weighted sum in registers.
// Online-softmax rescaling across tiles handles graphs larger than CAP.
template <bool USE_PTR>
__launch_bounds__(BLK, 2)
__global__ void pool_kernel(const float* __restrict__ nodes,
                            const float* __restrict__ W,
                            const float* __restrict__ bptr,
                            const int* __restrict__ ptr,
                            const int* __restrict__ g32,
                            int N,
                            float* __restrict__ out) {
    __shared__ float s_node[CAP * NDIM];  // 64 KB tile
    __shared__ float s_log[CAP];          // logits of tile
    __shared__ float s_red[8];            // [0..3] max, [4..7] sum

    const int tid = threadIdx.x;
    const int grp = tid >> 5;   // 0..7
    const int gl  = tid & 31;   // 0..31
    const int g   = blockIdx.x;

    int start, end;
    if (USE_PTR) {
        start = ptr[g];
        end   = ptr[g + 1];
    } else {
        // fallback: binary search directly on graph_idx (uniform across block)
        const size_t jprobe = ((size_t)N / 2) | 1;
        const bool is64 = (g32[jprobe] == 0);
        int lo = 0, hi = N;
        while (lo < hi) {
            int mid = (lo + hi) >> 1;
            int v = is64 ? g32[2 * (size_t)mid] : g32[mid];
            if (v < g) lo = mid + 1; else hi = mid;
        }
        start = lo;
        hi = N;
        while (lo < hi) {
            int mid = (lo + hi) >> 1;
            int v = is64 ? g32[2 * (size_t)mid] : g32[mid];
            if (v <= g) lo = mid + 1; else hi = mid;
        }
        end = lo;
    }

    const float4 wf = *(const float4*)(W + gl * 4);
    const float bb = bptr[0];

    float m = -INFINITY, ssum = 0.f;
    float4 acc = make_float4(0.f, 0.f, 0.f, 0.f);

    for (int t0 = start; t0 < end; t0 += CAP) {
        const int cnt = min(CAP, end - t0);
        __syncthreads();  // B0: prev tile's LDS reads done before overwrite

        // ---- Phase A: stage nodes to LDS, compute logits ----
        float lmax = -INFINITY;
        for (int j = grp; j < cnt; j += 8) {
            const float4 nf = *(const float4*)(nodes + (size_t)(t0 + j) * NDIM + gl * 4);
            *(float4*)(s_node + j * NDIM + gl * 4) = nf;
            float d = nf.x * wf.x + nf.y * wf.y + nf.z * wf.z + nf.w * wf.w;
            d += __shfl_xor(d, 1);
            d += __shfl_xor(d, 2);
            d += __shfl_xor(d, 4);
            d += __shfl_xor(d, 8);
            d += __shfl_xor(d, 16);   // all 32 lanes now hold the full dot
            d += bb;
            if (gl == 0) s_log[j] = d;
            lmax = fmaxf(lmax, d);
        }
        #pragma unroll
        for (int msk = 1; msk < 64; msk <<= 1)
            lmax = fmaxf(lmax, __shfl_xor(lmax, msk));
        const int wid = tid >> 6;
        if ((tid & 63) == 0) s_red[wid] = lmax;
        __syncthreads();  // B1: s_node/s_log/s_red(max) visible

        const float tm = fmaxf(fmaxf(s_red[0], s_red[1]), fmaxf(s_red[2], s_red[3]));
        const float nm = fmaxf(m, tm);
        const float scale = __expf(m - nm);  // m=-inf -> 0 on first tile
        acc.x *= scale; acc.y *= scale; acc.z *= scale; acc.w *= scale;
        ssum *= scale;
        m = nm;

        // ---- Phase B: weights + weighted accumulate from LDS ----
        float lsum = 0.f;
        for (int j = grp; j < cnt; j += 8) {
            const float w = __expf(s_log[j] - m);
            const float4 nf = *(const float4*)(s_node + j * NDIM + gl * 4);
            acc.x += w * nf.x; acc.y += w * nf.y;
            acc.z += w * nf.z; acc.w += w * nf.w;
            if (gl == 0) lsum += w;  // count each node's weight once
        }
        #pragma unroll
        for (int msk = 1; msk < 64; msk <<= 1)
            lsum += __shfl_xor(lsum, msk);
        if ((tid & 63) == 0) s_red[4 + wid] = lsum;
        __syncthreads();  // B2: sums visible
        ssum += s_red[4] + s_red[5] + s_red[6] + s_red[7];
    }

    // ---- Cross-group reduction (reuse s_node as 8x128 pool) ----
    __syncthreads();
    *(float4*)(s_node + grp * NDIM + gl * 4) = acc;
    __syncthreads();
    if (tid < NDIM) {
        float v = 0.f;
        #pragma unroll
        for (int k = 0; k < 8; ++k) v += s_node[k * NDIM + tid];
        out[(size_t)g * NDIM + tid] = v * (1.f / (ssum + 1e-8f));
    }
}

extern "C" void kernel_launch(void* const* d_in, const int* in_sizes, int n_in,
                              void* d_out, int out_size, void* d_ws, size_t ws_size,
                              hipStream_t stream) {
    const float* nodes = (const float*)d_in[0];
    const int*   gidx  = (const int*)d_in[1];
    // d_in[2] = n_graphs scalar (host-side constant; derived from out_size)
    const float* W     = (const float*)d_in[3];
    const float* b     = (const float*)d_in[4];
    float* out = (float*)d_out;

    const int N  = in_sizes[0] / NDIM;
    const int NG = out_size / NDIM;

    if (ws_size >= (size_t)(NG + 1) * sizeof(int)) {
        int* ptr = (int*)d_ws;
        offsets_kernel<<<2048, BLK, 0, stream>>>(gidx, N, NG, ptr);
        pool_kernel<true><<<NG, BLK, 0, stream>>>(nodes, W, b, ptr, gidx, N, out);
    } else {
        pool_kernel<false><<<NG, BLK, 0, stream>>>(nodes, W, b, nullptr, gidx, N, out);
    }
}

// Round 2
// 255.070 us; speedup vs baseline: 1.7964x; 1.7964x over previous
//
#include <hip/hip_runtime.h>

#define NDIM 128
#define RPT  16            // nodes per group per tile
#define RCAP (8 * RPT)     // 128 nodes per tile (8 groups)
#define BLK  256

// Build segment offsets ptr[g] = first i with graph_idx[i] >= g, ptr[NG] = N.
// Dtype-robust: probes an odd int32 slot near the middle; int64 high word == 0.
__global__ void offsets_kernel(const int* __restrict__ g32, int N, int NG,
                               int* __restrict__ ptr) {
    const size_t jprobe = ((size_t)N / 2) | 1;
    const bool is64 = (g32[jprobe] == 0);
    int i = blockIdx.x * blockDim.x + threadIdx.x;
    const int stride = gridDim.x * blockDim.x;
    for (; i < N; i += stride) {
        const int c = is64 ? g32[2 * (size_t)i] : g32[i];
        const int p = (i == 0) ? -1 : (is64 ? g32[2 * (size_t)(i - 1)] : g32[i - 1]);
        for (int g = p + 1; g <= c; ++g) ptr[g] = i;
        if (i == N - 1) {
            for (int g = c + 1; g <= NG; ++g) ptr[g] = N;
        }
    }
}

// One block per graph; 8 groups x 32 lanes. Group handles nodes j == grp (mod 8),
// lane gl covers dims [4*gl, 4*gl+4). Nodes staged in REGISTERS (16 float4/lane);
// logits live in registers (butterfly dot leaves full dot in all 32 lanes).
// One barrier per tile (block max, double-buffered LDS slots). Per-group softmax
// sums share the block-wide running max, merged once at the end.
template <bool USE_PTR>
__launch_bounds__(BLK, 4)
__global__ void pool_kernel(const float* __restrict__ nodes,
                            const float* __restrict__ W,
                            const float* __restrict__ bptr,
                            const int* __restrict__ ptr,
                            const int* __restrict__ g32,
                            int N,
                            float* __restrict__ out) {
    __shared__ float s_max[16];          // 8 groups x double buffer
    __shared__ float s_pool[8][NDIM];    // 4 KB final cross-group reduce
    __shared__ float s_sum[8];

    const int tid = threadIdx.x;
    const int grp = tid >> 5;   // 0..7
    const int gl  = tid & 31;   // 0..31
    const int g   = blockIdx.x;

    int start, end;
    if (USE_PTR) {
        start = ptr[g];
        end   = ptr[g + 1];
    } else {
        const size_t jprobe = ((size_t)N / 2) | 1;
        const bool is64 = (g32[jprobe] == 0);
        int lo = 0, hi = N;
        while (lo < hi) {
            int mid = (lo + hi) >> 1;
            int v = is64 ? g32[2 * (size_t)mid] : g32[mid];
            if (v < g) lo = mid + 1; else hi = mid;
        }
        start = lo;
        hi = N;
        while (lo < hi) {
            int mid = (lo + hi) >> 1;
            int v = is64 ? g32[2 * (size_t)mid] : g32[mid];
            if (v <= g) lo = mid + 1; else hi = mid;
        }
        end = lo;
    }

    const float4 wf = *(const float4*)(W + gl * 4);
    const float bb = bptr[0];

    float m = -INFINITY;
    float ssum = 0.f;                    // per-group denominator (scaled by m)
    float4 acc = make_float4(0.f, 0.f, 0.f, 0.f);
    int parity = 0;

    for (int t0 = start; t0 < end; t0 += RCAP) {
        const int cnt = end - t0;

        float4 nf[RPT];
        float  lg[RPT];
        float  lmax = -INFINITY;

        #pragma unroll
        for (int r = 0; r < RPT; ++r) {
            const int j = grp + 8 * r;
            if (j < cnt) {
                nf[r] = *(const float4*)(nodes + (size_t)(t0 + j) * NDIM + gl * 4);
                float d = nf[r].x * wf.x + nf[r].y * wf.y +
                          nf[r].z * wf.z + nf[r].w * wf.w;
                d += __shfl_xor(d, 1);
                d += __shfl_xor(d, 2);
                d += __shfl_xor(d, 4);
                d += __shfl_xor(d, 8);
                d += __shfl_xor(d, 16);  // all 32 lanes hold the full dot
                lg[r] = d + bb;
                lmax = fmaxf(lmax, lg[r]);
            } else {
                nf[r] = make_float4(0.f, 0.f, 0.f, 0.f);
                lg[r] = -INFINITY;
            }
        }

        // block max (all lanes of a group agree on lmax)
        if (gl == 0) s_max[parity * 8 + grp] = lmax;
        __syncthreads();
        float tm = s_max[parity * 8 + 0];
        #pragma unroll
        for (int k = 1; k < 8; ++k) tm = fmaxf(tm, s_max[parity * 8 + k]);
        parity ^= 1;

        const float nm = fmaxf(m, tm);
        const float scale = __expf(m - nm);   // m=-inf on first tile -> 0
        acc.x *= scale; acc.y *= scale; acc.z *= scale; acc.w *= scale;
        ssum *= scale;
        m = nm;

        #pragma unroll
        for (int r = 0; r < RPT; ++r) {
            const float w = __expf(lg[r] - m);   // -inf -> 0 for tail slots
            acc.x += w * nf[r].x; acc.y += w * nf[r].y;
            acc.z += w * nf[r].z; acc.w += w * nf[r].w;
            ssum += w;                           // same in all 32 lanes of group
        }
    }

    // cross-group reduction
    *(float4*)(&s_pool[grp][gl * 4]) = acc;
    if (gl == 0) s_sum[grp] = ssum;
    __syncthreads();
    if (tid < NDIM) {
        float v = 0.f;
        #pragma unroll
        for (int k = 0; k < 8; ++k) v += s_pool[k][tid];
        float tot = 0.f;
        #pragma unroll
        for (int k = 0; k < 8; ++k) tot += s_sum[k];
        out[(size_t)g * NDIM + tid] = v * (1.f / (tot + 1e-8f));
    }
}

extern "C" void kernel_launch(void* const* d_in, const int* in_sizes, int n_in,
                              void* d_out, int out_size, void* d_ws, size_t ws_size,
                              hipStream_t stream) {
    const float* nodes = (const float*)d_in[0];
    const int*   gidx  = (const int*)d_in[1];
    // d_in[2] = n_graphs scalar (derived from out_size instead)
    const float* W     = (const float*)d_in[3];
    const float* b     = (const float*)d_in[4];
    float* out = (float*)d_out;

    const int N  = in_sizes[0] / NDIM;
    const int NG = out_size / NDIM;

    if (ws_size >= (size_t)(NG + 1) * sizeof(int)) {
        int* ptr = (int*)d_ws;
        offsets_kernel<<<2048, BLK, 0, stream>>>(gidx, N, NG, ptr);
        pool_kernel<true><<<NG, BLK, 0, stream>>>(nodes, W, b, ptr, gidx, N, out);
    } else {
        pool_kernel<false><<<NG, BLK, 0, stream>>>(nodes, W, b, nullptr, gidx, N, out);
    }
}

// Round 3
// 198.006 us; speedup vs baseline: 2.3141x; 1.2882x over previous
//
#include <hip/hip_runtime.h>

#define NDIM 128
#define RPT  12            // nodes per 32-lane group per tile
#define TILE (2 * RPT)     // nodes per wave-tile (2 groups)
#define BLK  64            // ONE wave per block: no __syncthreads anywhere

// Build segment offsets ptr[g] = first i with graph_idx[i] >= g, ptr[NG] = N.
// Dtype-robust: probes an odd int32 slot near the middle; int64 high word == 0.
__global__ void offsets_kernel(const int* __restrict__ g32, int N, int NG,
                               int* __restrict__ ptr) {
    const size_t jprobe = ((size_t)N / 2) | 1;
    const bool is64 = (g32[jprobe] == 0);
    int i = blockIdx.x * blockDim.x + threadIdx.x;
    const int stride = gridDim.x * blockDim.x;
    for (; i < N; i += stride) {
        const int c = is64 ? g32[2 * (size_t)i] : g32[i];
        const int p = (i == 0) ? -1 : (is64 ? g32[2 * (size_t)(i - 1)] : g32[i - 1]);
        for (int g = p + 1; g <= c; ++g) ptr[g] = i;
        if (i == N - 1) {
            for (int g = c + 1; g <= NG; ++g) ptr[g] = N;
        }
    }
}

// One WAVE per graph. Two 32-lane groups; group grp handles nodes j==grp (mod 2),
// lane gl covers dims [4*gl, 4*gl+4). Nodes + logits live entirely in registers;
// butterfly dot leaves the full logit in all 32 lanes of the group. Cross-group
// max/sum via __shfl_xor(.,32). Zero LDS, zero barriers. Branchless tail:
// out-of-range slots load a duplicate valid row (harmless for max) and get w=0.
template <bool USE_PTR>
__launch_bounds__(BLK, 4)
__global__ void pool_kernel(const float* __restrict__ nodes,
                            const float* __restrict__ W,
                            const float* __restrict__ bptr,
                            const int* __restrict__ ptr,
                            const int* __restrict__ g32,
                            int N,
                            float* __restrict__ out) {
    const int tid = threadIdx.x;   // 0..63
    const int grp = tid >> 5;      // 0..1
    const int gl  = tid & 31;      // 0..31
    const int g   = blockIdx.x;

    int start, end;
    if (USE_PTR) {
        start = ptr[g];
        end   = ptr[g + 1];
    } else {
        const size_t jprobe = ((size_t)N / 2) | 1;
        const bool is64 = (g32[jprobe] == 0);
        int lo = 0, hi = N;
        while (lo < hi) {
            int mid = (lo + hi) >> 1;
            int v = is64 ? g32[2 * (size_t)mid] : g32[mid];
            if (v < g) lo = mid + 1; else hi = mid;
        }
        start = lo;
        hi = N;
        while (lo < hi) {
            int mid = (lo + hi) >> 1;
            int v = is64 ? g32[2 * (size_t)mid] : g32[mid];
            if (v <= g) lo = mid + 1; else hi = mid;
        }
        end = lo;
    }

    if (end <= start) {   // empty graph: reference yields zeros
        if (tid < 32) {
            float4 z = make_float4(0.f, 0.f, 0.f, 0.f);
            *(float4*)(out + (size_t)g * NDIM + gl * 4) = z;
        }
        return;
    }

    const float4 wf = *(const float4*)(W + gl * 4);
    const float bb = bptr[0];

    float m = -INFINITY;
    float ssum = 0.f;
    float4 acc = make_float4(0.f, 0.f, 0.f, 0.f);

    for (int t0 = start; t0 < end; t0 += TILE) {
        const int cnt = end - t0;          // >= 1

        float4 nf[RPT];
        float  lg[RPT];

        #pragma unroll
        for (int r = 0; r < RPT; ++r) {    // all loads issued unconditionally
            const int j  = grp + 2 * r;
            const int jc = min(j, cnt - 1);
            nf[r] = *(const float4*)(nodes + (size_t)(t0 + jc) * NDIM + gl * 4);
        }

        float lmax = -INFINITY;
        #pragma unroll
        for (int r = 0; r < RPT; ++r) {
            float d = nf[r].x * wf.x + nf[r].y * wf.y +
                      nf[r].z * wf.z + nf[r].w * wf.w;
            d += __shfl_xor(d, 1);
            d += __shfl_xor(d, 2);
            d += __shfl_xor(d, 4);
            d += __shfl_xor(d, 8);
            d += __shfl_xor(d, 16);        // full dot in all 32 group lanes
            lg[r] = d + bb;
            lmax = fmaxf(lmax, lg[r]);     // duplicated rows can't change max
        }
        lmax = fmaxf(lmax, __shfl_xor(lmax, 32));   // cross-group max

        const float nm = fmaxf(m, lmax);
        const float scale = __expf(m - nm);          // first tile: exp(-inf)=0
        acc.x *= scale; acc.y *= scale; acc.z *= scale; acc.w *= scale;
        ssum *= scale;
        m = nm;

        #pragma unroll
        for (int r = 0; r < RPT; ++r) {
            const int j = grp + 2 * r;
            const float w = (j < cnt) ? __expf(lg[r] - m) : 0.f;
            acc.x += w * nf[r].x; acc.y += w * nf[r].y;
            acc.z += w * nf[r].z; acc.w += w * nf[r].w;
            ssum += w;                      // identical across the 32 group lanes
        }
    }

    // merge the two groups (dims are identical per lane-id mod 32)
    acc.x += __shfl_xor(acc.x, 32);
    acc.y += __shfl_xor(acc.y, 32);
    acc.z += __shfl_xor(acc.z, 32);
    acc.w += __shfl_xor(acc.w, 32);
    ssum  += __shfl_xor(ssum, 32);

    if (tid < 32) {
        const float inv = 1.f / (ssum + 1e-8f);
        float4 o;
        o.x = acc.x * inv; o.y = acc.y * inv;
        o.z = acc.z * inv; o.w = acc.w * inv;
        *(float4*)(out + (size_t)g * NDIM + gl * 4) = o;
    }
}

extern "C" void kernel_launch(void* const* d_in, const int* in_sizes, int n_in,
                              void* d_out, int out_size, void* d_ws, size_t ws_size,
                              hipStream_t stream) {
    const float* nodes = (const float*)d_in[0];
    const int*   gidx  = (const int*)d_in[1];
    // d_in[2] = n_graphs scalar (derived from out_size instead)
    const float* W     = (const float*)d_in[3];
    const float* b     = (const float*)d_in[4];
    float* out = (float*)d_out;

    const int N  = in_sizes[0] / NDIM;
    const int NG = out_size / NDIM;

    if (ws_size >= (size_t)(NG + 1) * sizeof(int)) {
        int* ptr = (int*)d_ws;
        offsets_kernel<<<2048, 256, 0, stream>>>(gidx, N, NG, ptr);
        pool_kernel<true><<<NG, BLK, 0, stream>>>(nodes, W, b, ptr, gidx, N, out);
    } else {
        pool_kernel<false><<<NG, BLK, 0, stream>>>(nodes, W, b, nullptr, gidx, N, out);
    }
}

// Round 5
// 165.120 us; speedup vs baseline: 2.7750x; 1.1992x over previous
//
#include <hip/hip_runtime.h>

#define NDIM 128
#define RPT  12            // nodes per 32-lane group per tile
#define TILE (2 * RPT)     // nodes per wave-tile (2 groups)
#define BLK  64            // ONE wave per block: no __syncthreads anywhere

typedef float floatx4 __attribute__((ext_vector_type(4)));  // native vec for nontemporal builtins

// Build segment offsets ptr[g] = first i with graph_idx[i] >= g, ptr[NG] = N.
// Dtype-robust: probes an odd int32 slot near the middle; int64 high word == 0.
__global__ void offsets_kernel(const int* __restrict__ g32, int N, int NG,
                               int* __restrict__ ptr) {
    const size_t jprobe = ((size_t)N / 2) | 1;
    const bool is64 = (g32[jprobe] == 0);
    int i = blockIdx.x * blockDim.x + threadIdx.x;
    const int stride = gridDim.x * blockDim.x;
    for (; i < N; i += stride) {
        const int c = is64 ? g32[2 * (size_t)i] : g32[i];
        const int p = (i == 0) ? -1 : (is64 ? g32[2 * (size_t)(i - 1)] : g32[i - 1]);
        for (int g = p + 1; g <= c; ++g) ptr[g] = i;
        if (i == N - 1) {
            for (int g = c + 1; g <= NG; ++g) ptr[g] = N;
        }
    }
}

// One WAVE per graph. Two 32-lane groups; group grp handles nodes j==grp (mod 2),
// lane gl covers dims [4*gl, 4*gl+4). Nodes + logits live entirely in registers;
// butterfly dot leaves the full logit in all 32 lanes of the group. Cross-group
// max/sum via __shfl_xor(.,32). Zero LDS, zero barriers.
// Steady state: unconditional full tiles (no min, no predicated weight,
// nontemporal loads — stream-once data). One guarded tail tile at the end.
template <bool USE_PTR>
__launch_bounds__(BLK, 4)
__global__ void pool_kernel(const float* __restrict__ nodes,
                            const float* __restrict__ W,
                            const float* __restrict__ bptr,
                            const int* __restrict__ ptr,
                            const int* __restrict__ g32,
                            int N,
                            float* __restrict__ out) {
    const int tid = threadIdx.x;   // 0..63
    const int grp = tid >> 5;      // 0..1
    const int gl  = tid & 31;      // 0..31
    const int g   = blockIdx.x;

    int start, end;
    if (USE_PTR) {
        start = ptr[g];
        end   = ptr[g + 1];
    } else {
        const size_t jprobe = ((size_t)N / 2) | 1;
        const bool is64 = (g32[jprobe] == 0);
        int lo = 0, hi = N;
        while (lo < hi) {
            int mid = (lo + hi) >> 1;
            int v = is64 ? g32[2 * (size_t)mid] : g32[mid];
            if (v < g) lo = mid + 1; else hi = mid;
        }
        start = lo;
        hi = N;
        while (lo < hi) {
            int mid = (lo + hi) >> 1;
            int v = is64 ? g32[2 * (size_t)mid] : g32[mid];
            if (v <= g) lo = mid + 1; else hi = mid;
        }
        end = lo;
    }

    if (end <= start) {   // empty graph: reference yields zeros
        if (tid < 32) {
            floatx4 z = (floatx4)(0.f);
            *(floatx4*)(out + (size_t)g * NDIM + gl * 4) = z;
        }
        return;
    }

    const floatx4 wf = *(const floatx4*)(W + gl * 4);
    const float bb = bptr[0];

    float m = -INFINITY;
    float ssum = 0.f;
    floatx4 acc = (floatx4)(0.f);

    int t0 = start;

    // ---- full tiles: no bounds checks anywhere ----
    for (; t0 + TILE <= end; t0 += TILE) {
        floatx4 nf[RPT];
        float   lg[RPT];

        #pragma unroll
        for (int r = 0; r < RPT; ++r) {
            const floatx4* p = (const floatx4*)(nodes + (size_t)(t0 + grp + 2 * r) * NDIM + gl * 4);
            nf[r] = __builtin_nontemporal_load(p);
        }

        float lmax = -INFINITY;
        #pragma unroll
        for (int r = 0; r < RPT; ++r) {
            float d = nf[r].x * wf.x + nf[r].y * wf.y +
                      nf[r].z * wf.z + nf[r].w * wf.w;
            d += __shfl_xor(d, 1);
            d += __shfl_xor(d, 2);
            d += __shfl_xor(d, 4);
            d += __shfl_xor(d, 8);
            d += __shfl_xor(d, 16);        // full dot in all 32 group lanes
            lg[r] = d + bb;
            lmax = fmaxf(lmax, lg[r]);
        }
        lmax = fmaxf(lmax, __shfl_xor(lmax, 32));   // cross-group max

        const float nm = fmaxf(m, lmax);
        const float scale = __expf(m - nm);          // first tile: exp(-inf)=0
        acc *= scale;
        ssum *= scale;
        m = nm;

        #pragma unroll
        for (int r = 0; r < RPT; ++r) {
            const float w = __expf(lg[r] - m);
            acc += w * nf[r];
            ssum += w;                      // identical across the 32 group lanes
        }
    }

    // ---- tail tile (at most one): branchless duplicate loads, w=0 masks ----
    if (t0 < end) {
        const int cnt = end - t0;          // 1..TILE-1

        floatx4 nf[RPT];
        float   lg[RPT];

        #pragma unroll
        for (int r = 0; r < RPT; ++r) {
            const int j  = grp + 2 * r;
            const int jc = min(j, cnt - 1);
            nf[r] = *(const floatx4*)(nodes + (size_t)(t0 + jc) * NDIM + gl * 4);
        }

        float lmax = -INFINITY;
        #pragma unroll
        for (int r = 0; r < RPT; ++r) {
            float d = nf[r].x * wf.x + nf[r].y * wf.y +
                      nf[r].z * wf.z + nf[r].w * wf.w;
            d += __shfl_xor(d, 1);
            d += __shfl_xor(d, 2);
            d += __shfl_xor(d, 4);
            d += __shfl_xor(d, 8);
            d += __shfl_xor(d, 16);
            lg[r] = d + bb;
            lmax = fmaxf(lmax, lg[r]);     // duplicated rows can't change max
        }
        lmax = fmaxf(lmax, __shfl_xor(lmax, 32));

        const float nm = fmaxf(m, lmax);
        const float scale = __expf(m - nm);
        acc *= scale;
        ssum *= scale;
        m = nm;

        #pragma unroll
        for (int r = 0; r < RPT; ++r) {
            const int j = grp + 2 * r;
            const float w = (j < cnt) ? __expf(lg[r] - m) : 0.f;
            acc += w * nf[r];
            ssum += w;
        }
    }

    // merge the two groups (dims are identical per lane-id mod 32)
    acc.x += __shfl_xor(acc.x, 32);
    acc.y += __shfl_xor(acc.y, 32);
    acc.z += __shfl_xor(acc.z, 32);
    acc.w += __shfl_xor(acc.w, 32);
    ssum  += __shfl_xor(ssum, 32);

    if (tid < 32) {
        const float inv = 1.f / (ssum + 1e-8f);
        floatx4 o = acc * inv;
        *(floatx4*)(out + (size_t)g * NDIM + gl * 4) = o;
    }
}

extern "C" void kernel_launch(void* const* d_in, const int* in_sizes, int n_in,
                              void* d_out, int out_size, void* d_ws, size_t ws_size,
                              hipStream_t stream) {
    const float* nodes = (const float*)d_in[0];
    const int*   gidx  = (const int*)d_in[1];
    // d_in[2] = n_graphs scalar (derived from out_size instead)
    const float* W     = (const float*)d_in[3];
    const float* b     = (const float*)d_in[4];
    float* out = (float*)d_out;

    const int N  = in_sizes[0] / NDIM;
    const int NG = out_size / NDIM;

    if (ws_size >= (size_t)(NG + 1) * sizeof(int)) {
        int* ptr = (int*)d_ws;
        offsets_kernel<<<2048, 256, 0, stream>>>(gidx, N, NG, ptr);
        pool_kernel<true><<<NG, BLK, 0, stream>>>(nodes, W, b, ptr, gidx, N, out);
    } else {
        pool_kernel<false><<<NG, BLK, 0, stream>>>(nodes, W, b, nullptr, gidx, N, out);
    }
}